// Round 15
// baseline (121.730 us; speedup 1.0000x reference)
//
#include <hip/hip_runtime.h>
#include <hip/hip_bf16.h>
#include <math.h>

#define BB 4
#define SS 2048
#define DD 512
#define HH 8
#define DHH 64
#define KPAD 72   // bf16 LDS row stride: 144B; 32-lane b128 column reads spread 8 dwords/bank = conflict-free
#define GPAD 72
#define LOG2E 1.44269504088896340736f

typedef __attribute__((ext_vector_type(8))) short short8;
typedef __attribute__((ext_vector_type(4))) float f32x4;
typedef __attribute__((ext_vector_type(16))) float f32x16;
typedef __attribute__((ext_vector_type(4))) unsigned short ushort4v;
typedef unsigned short ushort;
typedef unsigned char uchar;
typedef unsigned int u32;
typedef unsigned long long u64;

static __device__ __forceinline__ ushort f2b(float x) {
    __hip_bfloat16 h = __float2bfloat16(x);   // RNE
    return *reinterpret_cast<ushort*>(&h);
}

// ---------------------------------------------------------------- T5 bucket
__device__ __forceinline__ int t5_bucket(int rel) {
    int rb = (rel > 0) ? 16 : 0;
    int ap = rel < 0 ? -rel : rel;
    if (ap < 8) return rb + ap;
    float t = logf((float)ap * 0.125f) / 2.77258872985839844f * 8.0f;
    int large = 8 + (int)t;
    if (large > 15) large = 15;
    return rb + large;
}

// ---------------------------------------------------------------- merged prep kernel (saves 2 launches)
// bid <1024: mask->bitmask; 1024-1151: bias LUT (f32, xLOG2E); 1152-1407: weight transpose+cvt
__global__ __launch_bounds__(256) void prep_kernel(const void* __restrict__ mask, u64* __restrict__ mwords,
                                                   const float* __restrict__ rel_bias, float* __restrict__ btbl,
                                                   const float* __restrict__ W0, const float* __restrict__ W1,
                                                   const float* __restrict__ W2, const float* __restrict__ W3,
                                                   ushort* __restrict__ T0, ushort* __restrict__ T1,
                                                   ushort* __restrict__ T2, ushort* __restrict__ T3) {
    __shared__ float tile[64][65];
    __shared__ int sflag;
    const int bid = blockIdx.x;
    const int tid = threadIdx.x;

    if (bid < 1024) {
        // ---- mask -> bitmask (u64 per 64 cols), dtype detect fused
        if (tid == 0) sflag = 0;
        __syncthreads();
        u32 probe = ((const u32*)mask)[tid];      // first 1KB: bytes -> words >1 w.h.p.
        if (__any(probe > 1u) && (tid & 63) == 0) sflag = 1;
        __syncthreads();
        const bool bytemode = sflag != 0;

        int idx = bid * 256 + tid;                // (b*S + q)*32 + w
        int w = idx & 31;
        int row = idx >> 5;
        u64 bits = 0ull;
        if (bytemode) {
            const uint4* p4 = (const uint4*)((const uchar*)mask + (size_t)row * SS + w * 64);
#pragma unroll
            for (int i = 0; i < 4; ++i) {
                uint4 v = p4[i];
                unsigned int a[4] = {v.x, v.y, v.z, v.w};
#pragma unroll
                for (int j = 0; j < 4; ++j)
#pragma unroll
                    for (int byte = 0; byte < 4; ++byte)
                        if ((a[j] >> (byte * 8)) & 0xffu) bits |= 1ull << (i * 16 + j * 4 + byte);
            }
        } else {
            const int4* p4 = (const int4*)((const int*)mask + (size_t)row * SS + w * 64);
#pragma unroll
            for (int i = 0; i < 16; ++i) {
                int4 v = p4[i];
                if (v.x) bits |= 1ull << (i * 4 + 0);
                if (v.y) bits |= 1ull << (i * 4 + 1);
                if (v.z) bits |= 1ull << (i * 4 + 2);
                if (v.w) bits |= 1ull << (i * 4 + 3);
            }
        }
        mwords[idx] = bits;
    } else if (bid < 1152) {
        // ---- bias LUT: tbl[h][j], j in [0,4096): LOG2E * bias(delta = j - 2047)
        int i = (bid - 1024) * 256 + tid;
        int h = i >> 12;
        int d = (i & 4095) - 2047;
        btbl[i] = LOG2E * rel_bias[t5_bucket(d) * HH + h];
    } else {
        // ---- weight transpose + cvt: Wt[n][k] = bf16(W[k][n])
        const int b2 = bid - 1152;
        const int z = b2 >> 6;
        const float* W = z == 0 ? W0 : z == 1 ? W1 : z == 2 ? W2 : W3;
        ushort*     T = z == 0 ? T0 : z == 1 ? T1 : z == 2 ? T2 : T3;
        const int n0 = (b2 & 7) * 64, k0 = ((b2 >> 3) & 7) * 64;
        const int tr = tid >> 4, tc = tid & 15;
#pragma unroll
        for (int i = 0; i < 4; ++i) {
            int r = i * 16 + tr;
            float4 v = *(const float4*)&W[(size_t)(k0 + r) * 512 + n0 + tc * 4];
            tile[r][tc * 4 + 0] = v.x; tile[r][tc * 4 + 1] = v.y;
            tile[r][tc * 4 + 2] = v.z; tile[r][tc * 4 + 3] = v.w;
        }
        __syncthreads();
#pragma unroll
        for (int i = 0; i < 4; ++i) {
            int rn = i * 16 + tr;
            ushort4v o;
#pragma unroll
            for (int j = 0; j < 4; ++j) o[j] = f2b(tile[tc * 4 + j][rn]);
            *(ushort4v*)&T[(size_t)(n0 + rn) * 512 + k0 + tc * 4] = o;
        }
    }
}

// ---------------------------------------------------------------- merged QKV projection GEMM (bf16 MFMA), 128x128 tile
// grid (64,4,3). T14 prefetch: next K-tile loaded to regs while MFMAs run (loads no longer barrier-exposed).
__global__ __launch_bounds__(256) void qkv_gemm(const float* __restrict__ Xq, const float* __restrict__ Xk,
                                                const float* __restrict__ Xv,
                                                const ushort* __restrict__ Wqt, const ushort* __restrict__ Wkt,
                                                const ushort* __restrict__ Wvt,
                                                const float* __restrict__ bqp, const float* __restrict__ bkp,
                                                const float* __restrict__ bvp,
                                                ushort* __restrict__ Yq, ushort* __restrict__ Yk,
                                                ushort* __restrict__ Yv) {
    __shared__ ushort Als[128 * GPAD];
    __shared__ ushort Bls[128 * GPAD];
    const int z = blockIdx.z;
    const float* A    = z == 0 ? Xq : z == 1 ? Xk : Xv;
    const ushort* Bt  = z == 0 ? Wqt : z == 1 ? Wkt : Wvt;
    const float* bias = z == 0 ? bqp : z == 1 ? bkp : bvp;
    const float scale = z == 0 ? 0.125f * LOG2E : 1.0f;   // q pre-scaled into exp2 domain

    const int tid = threadIdx.x;
    const int lane = tid & 63;
    const int wid = tid >> 6;
    const int lq = lane & 15, lg = lane >> 4;
    const int wr = wid >> 1, wc = wid & 1;
    const int bm = blockIdx.x * 128;
    const int bn = blockIdx.y * 128;

    f32x4 acc[4][4];
#pragma unroll
    for (int m = 0; m < 4; ++m)
#pragma unroll
        for (int n = 0; n < 4; ++n) acc[m][n] = (f32x4){0.f, 0.f, 0.f, 0.f};

    const int sr = tid >> 3;
    const int sc = (tid & 7) * 8;

    // prologue: prefetch K-tile 0 into regs (fp32 A converted at load)
    short8 sa[4], sb[4];
#pragma unroll
    for (int i = 0; i < 4; ++i) {
        int r = sr + i * 32;
        float4 u = *(const float4*)(A + (size_t)(bm + r) * 512 + sc);
        float4 v = *(const float4*)(A + (size_t)(bm + r) * 512 + sc + 4);
        short8 av;
        av[0] = (short)f2b(u.x); av[1] = (short)f2b(u.y); av[2] = (short)f2b(u.z); av[3] = (short)f2b(u.w);
        av[4] = (short)f2b(v.x); av[5] = (short)f2b(v.y); av[6] = (short)f2b(v.z); av[7] = (short)f2b(v.w);
        sa[i] = av;
        sb[i] = *(const short8*)(Bt + (size_t)(bn + r) * 512 + sc);
    }

    for (int k0 = 0; k0 < 512; k0 += 64) {
        // commit staged tile to LDS
#pragma unroll
        for (int i = 0; i < 4; ++i) {
            int r = sr + i * 32;
            *(short8*)&Als[r * GPAD + sc] = sa[i];
            *(short8*)&Bls[r * GPAD + sc] = sb[i];
        }
        __syncthreads();
        // prefetch next K-tile (latency hides under MFMAs below)
        if (k0 < 448) {
#pragma unroll
            for (int i = 0; i < 4; ++i) {
                int r = sr + i * 32;
                float4 u = *(const float4*)(A + (size_t)(bm + r) * 512 + k0 + 64 + sc);
                float4 v = *(const float4*)(A + (size_t)(bm + r) * 512 + k0 + 64 + sc + 4);
                short8 av;
                av[0] = (short)f2b(u.x); av[1] = (short)f2b(u.y); av[2] = (short)f2b(u.z); av[3] = (short)f2b(u.w);
                av[4] = (short)f2b(v.x); av[5] = (short)f2b(v.y); av[6] = (short)f2b(v.z); av[7] = (short)f2b(v.w);
                sa[i] = av;
                sb[i] = *(const short8*)(Bt + (size_t)(bn + r) * 512 + k0 + 64 + sc);
            }
        }
#pragma unroll
        for (int kk = 0; kk < 2; ++kk) {
            short8 af[4], bf[4];
#pragma unroll
            for (int m = 0; m < 4; ++m)
                af[m] = *(short8*)&Als[(wr * 64 + m * 16 + lq) * GPAD + kk * 32 + lg * 8];
#pragma unroll
            for (int n = 0; n < 4; ++n)
                bf[n] = *(short8*)&Bls[(wc * 64 + n * 16 + lq) * GPAD + kk * 32 + lg * 8];
#pragma unroll
            for (int m = 0; m < 4; ++m)
#pragma unroll
                for (int n = 0; n < 4; ++n)
                    acc[m][n] = __builtin_amdgcn_mfma_f32_16x16x32_bf16(af[m], bf[n], acc[m][n], 0, 0, 0);
        }
        __syncthreads();   // all LDS reads done before next commit
    }

    float bv[4];
#pragma unroll
    for (int n = 0; n < 4; ++n) bv[n] = bias[bn + wc * 64 + n * 16 + lq];

    if (z == 2) {
        const int blk = bm >> 11;
        const int s0 = (bm & 2047) + wr * 64 + lg * 4;
#pragma unroll
        for (int m = 0; m < 4; ++m)
#pragma unroll
            for (int n = 0; n < 4; ++n) {
                int col = bn + wc * 64 + n * 16 + lq;
                ushort4v o;
#pragma unroll
                for (int r = 0; r < 4; ++r) o[r] = f2b(acc[m][n][r] + bv[n]);
                *(ushort4v*)&Yv[((size_t)(blk * 512 + col)) * SS + s0 + m * 16] = o;
            }
    } else {
        ushort* Y = z ? Yk : Yq;
#pragma unroll
        for (int m = 0; m < 4; ++m)
#pragma unroll
            for (int r = 0; r < 4; ++r) {
                int row = bm + wr * 64 + m * 16 + lg * 4 + r;
#pragma unroll
                for (int n = 0; n < 4; ++n) {
                    int col = bn + wc * 64 + n * 16 + lq;
                    Y[(size_t)row * 512 + col] = f2b((acc[m][n][r] + bv[n]) * scale);
                }
            }
    }
}

// ---------------------------------------------------------------- final output GEMM (bf16 A, fp32 out), 128x128, grid (64,4)
__global__ __launch_bounds__(256) void out_gemm(const ushort* __restrict__ A,
                                                const ushort* __restrict__ Bt,
                                                const float* __restrict__ bias,
                                                float* __restrict__ Y) {
    __shared__ ushort Als[128 * GPAD];
    __shared__ ushort Bls[128 * GPAD];
    const int tid = threadIdx.x;
    const int lane = tid & 63;
    const int wid = tid >> 6;
    const int lq = lane & 15, lg = lane >> 4;
    const int wr = wid >> 1, wc = wid & 1;
    const int bm = blockIdx.x * 128;
    const int bn = blockIdx.y * 128;

    f32x4 acc[4][4];
#pragma unroll
    for (int m = 0; m < 4; ++m)
#pragma unroll
        for (int n = 0; n < 4; ++n) acc[m][n] = (f32x4){0.f, 0.f, 0.f, 0.f};

    const int sr = tid >> 3;
    const int sc = (tid & 7) * 8;

    // prologue: prefetch K-tile 0
    short8 sa[4], sb[4];
#pragma unroll
    for (int i = 0; i < 4; ++i) {
        int r = sr + i * 32;
        sa[i] = *(const short8*)(A + (size_t)(bm + r) * 512 + sc);
        sb[i] = *(const short8*)(Bt + (size_t)(bn + r) * 512 + sc);
    }

    for (int k0 = 0; k0 < 512; k0 += 64) {
#pragma unroll
        for (int i = 0; i < 4; ++i) {
            int r = sr + i * 32;
            *(short8*)&Als[r * GPAD + sc] = sa[i];
            *(short8*)&Bls[r * GPAD + sc] = sb[i];
        }
        __syncthreads();
        if (k0 < 448) {
#pragma unroll
            for (int i = 0; i < 4; ++i) {
                int r = sr + i * 32;
                sa[i] = *(const short8*)(A + (size_t)(bm + r) * 512 + k0 + 64 + sc);
                sb[i] = *(const short8*)(Bt + (size_t)(bn + r) * 512 + k0 + 64 + sc);
            }
        }
#pragma unroll
        for (int kk = 0; kk < 2; ++kk) {
            short8 af[4], bf[4];
#pragma unroll
            for (int m = 0; m < 4; ++m)
                af[m] = *(short8*)&Als[(wr * 64 + m * 16 + lq) * GPAD + kk * 32 + lg * 8];
#pragma unroll
            for (int n = 0; n < 4; ++n)
                bf[n] = *(short8*)&Bls[(wc * 64 + n * 16 + lq) * GPAD + kk * 32 + lg * 8];
#pragma unroll
            for (int m = 0; m < 4; ++m)
#pragma unroll
                for (int n = 0; n < 4; ++n)
                    acc[m][n] = __builtin_amdgcn_mfma_f32_16x16x32_bf16(af[m], bf[n], acc[m][n], 0, 0, 0);
        }
        __syncthreads();
    }

    float bv[4];
#pragma unroll
    for (int n = 0; n < 4; ++n) bv[n] = bias[bn + wc * 64 + n * 16 + lq];
#pragma unroll
    for (int m = 0; m < 4; ++m)
#pragma unroll
        for (int r = 0; r < 4; ++r) {
            int row = bm + wr * 64 + m * 16 + lg * 4 + r;
#pragma unroll
            for (int n = 0; n < 4; ++n) {
                int col = bn + wc * 64 + n * 16 + lq;
                Y[(size_t)row * 512 + col] = acc[m][n][r] + bv[n];
            }
        }
}

// ---------------------------------------------------------------- MFMA flash attention (r13 structure + T5 setprio around MFMA clusters)
// 512 thr (8 warps), split-KV, 128 q-rows/block, swapped QK^T/PV (lane = q), fixed-max exp2 softmax.
// Bias folded into QK MFMA C-input (f32 LDS reads). Mask = branchless sign-extend AND.
// l = sum_k p via all-ones-A MFMA. Pack via v_cvt_pk_bf16_f32; half-exchange via permlane32_swap.
// LESSONS: launch_bounds stays (512,4) — (512,6) spilled (r10); no const-bias branch (r11 spill); KPAD=72 everywhere (r12).
// setprio rationale: 2 blocks/CU co-resident, not cross-block barrier-synced -> m191 regime (+4-7% attn).
__global__ __launch_bounds__(512, 4) void attn_kernel(const ushort* __restrict__ Qg, const ushort* __restrict__ Kg,
                                                      const ushort* __restrict__ vT, const u64* __restrict__ mwords,
                                                      const float* __restrict__ btbl, ushort* __restrict__ ctxb) {
    __shared__ ushort KV[4][64 * KPAD];   // K0,K1,V0,V1; reused as fp32 combine buffer
    __shared__ ushort QT[128 * KPAD];     // Q staging -> f32 bias table (16KB) -> epilogue transpose
    float* tbl = (float*)QT;

    const int bid = blockIdx.x;                       // grid = 512
    const int wk = ((bid & 7) << 6) | (bid >> 3);     // XCD-chunked remap (512 % 8 == 0: bijective)
    const int qb = wk & 15;
    const int h  = (wk >> 4) & 7;
    const int b  = wk >> 7;
    const int q0 = qb * 128;

    const int tid  = threadIdx.x;
    const int wid  = tid >> 6;
    const int lane = tid & 63;
    const int lq32 = lane & 31;
    const int hi   = lane >> 5;
    const int seg  = wid >> 2;
    const int qw   = wid & 3;

    const u64* mrow = mwords + (size_t)b * SS * 32;
    const int qg = q0 + qw * 32 + lq32;

    // ---- stage Q tile (128 x 64)
    {
        const int r = tid >> 2;
        const int c = (tid & 3) * 16;
        const size_t g = ((size_t)(b * SS + q0 + r)) * DD + h * DHH + c;
        *(short8*)&QT[r * KPAD + c]     = *(const short8*)(Qg + g);
        *(short8*)&QT[r * KPAD + c + 8] = *(const short8*)(Qg + g + 8);
    }
    __syncthreads();

    short8 qf[4];
#pragma unroll
    for (int dch = 0; dch < 4; ++dch)
        qf[dch] = *(short8*)&QT[(qw * 32 + lq32) * KPAD + dch * 16 + hi * 8];
    __syncthreads();   // all Q reads done before bias table overwrites QT

    // ---- f32 bias table for this head -> LDS (16 KB)
    {
        const float4* src = (const float4*)(btbl + (size_t)h * 4096);
        float4* dst = (float4*)tbl;
        dst[tid]       = src[tid];
        dst[tid + 512] = src[tid + 512];
    }

    f32x16 acc0, acc1, accl;
#pragma unroll
    for (int i = 0; i < 16; ++i) { acc0[i] = 0.f; acc1[i] = 0.f; accl[i] = 0.f; }

    short8 ones;
#pragma unroll
    for (int i = 0; i < 8; ++i) ones[i] = (short)0x3F80;   // bf16 1.0

    // staging role: tile = tid>>7 (0:K0 1:K1 2:V0 3:V1), wave-uniform
    const int stile = tid >> 7;
    const int sidx = tid & 127;
    const int srow = sidx >> 1;
    const int scol = (sidx & 1) * 32;
    const size_t kbaseK = ((size_t)(b * SS + (stile & 1) * 1024 + srow)) * DD + h * DHH + scol;
    const size_t kbaseV = ((size_t)(b * DD + h * DHH + srow)) * SS + (stile & 1) * 1024 + scol;

    // prologue: prefetch tile 0 into regs
    short8 stg[4];
    {
        const ushort* sp = (stile < 2) ? (Kg + kbaseK) : (vT + kbaseV);
#pragma unroll
        for (int j = 0; j < 4; ++j) stg[j] = *(const short8*)(sp + j * 8);
    }

    const float* tbp_base = tbl + (2047 + hi * 4 - qg);

    for (int t = 0; t < 16; ++t) {
        __syncthreads();   // prev tiles consumed (t=0: bias table stores complete)
        {
            ushort* dst = &KV[stile][srow * KPAD + scol];
#pragma unroll
            for (int j = 0; j < 4; ++j) *(short8*)(dst + j * 8) = stg[j];
        }
        __syncthreads();
        if (t < 15) {   // prefetch t+1 (latency hides under compute below)
            const ushort* sp = (stile < 2) ? (Kg + kbaseK + (size_t)(t + 1) * 64 * DD)
                                           : (vT + kbaseV + (t + 1) * 64);
#pragma unroll
            for (int j = 0; j < 4; ++j) stg[j] = *(const short8*)(sp + j * 8);
        }

        const ushort* Ks = KV[seg];
        const ushort* Vt = KV[2 + seg];
        const int ktw = seg * 16 + t;
        const u64 wv = mrow[(size_t)qg * 32 + ktw];

        // ---- QK^T swapped, C initialized with bias (exp2 domain): col=q, row=k=crow(reg,hi)+sub*32
        const float* tbp = tbp_base + ktw * 64;
        f32x16 st0, st1;
#pragma unroll
        for (int r = 0; r < 16; ++r) {
            const int br = (r & 3) + 8 * (r >> 2);
            st0[r] = tbp[br];
            st1[r] = tbp[32 + br];
        }
        __builtin_amdgcn_s_setprio(1);
#pragma unroll
        for (int dch = 0; dch < 4; ++dch) {
            short8 kf0 = *(short8*)&Ks[lq32 * KPAD + dch * 16 + hi * 8];
            short8 kf1 = *(short8*)&Ks[(32 + lq32) * KPAD + dch * 16 + hi * 8];
            st0 = __builtin_amdgcn_mfma_f32_32x32x16_bf16(kf0, qf[dch], st0, 0, 0, 0);
            st1 = __builtin_amdgcn_mfma_f32_32x32x16_bf16(kf1, qf[dch], st1, 0, 0, 0);
        }
        __builtin_amdgcn_s_setprio(0);

        // ---- exp2 + branchless mask-zero (keep = sext of inverted mask bit)
        const u32 mi0 = ~(((u32)wv) >> (hi * 4));
        const u32 mi1 = ~(((u32)(wv >> 32)) >> (hi * 4));
        float p0[16], p1[16];
#pragma unroll
        for (int r = 0; r < 16; ++r) {
            const int br = (r & 3) + 8 * (r >> 2);
            float e0 = __builtin_amdgcn_exp2f(st0[r]);
            float e1 = __builtin_amdgcn_exp2f(st1[r]);
            u32 k0 = (u32)(((int)(mi0 << (31 - br))) >> 31);
            u32 k1 = (u32)(((int)(mi1 << (31 - br))) >> 31);
            p0[r] = __uint_as_float(__float_as_uint(e0) & k0);
            p1[r] = __uint_as_float(__float_as_uint(e1) & k1);
        }

        // ---- pack P pairs via v_cvt_pk_bf16_f32; half-exchange via permlane32_swap
        u32 W[16];
#pragma unroll
        for (int w = 0; w < 8; ++w) {
            asm("v_cvt_pk_bf16_f32 %0, %1, %2" : "=v"(W[w])     : "v"(p0[2 * w]), "v"(p0[2 * w + 1]));
            asm("v_cvt_pk_bf16_f32 %0, %1, %2" : "=v"(W[8 + w]) : "v"(p1[2 * w]), "v"(p1[2 * w + 1]));
        }
        short8 pf[4];
#pragma unroll
        for (int g = 0; g < 4; ++g) {
            u32 A = W[g * 4 + 0], Bw = W[g * 4 + 1], C = W[g * 4 + 2], D = W[g * 4 + 3];
            asm("v_permlane32_swap_b32 %0, %1" : "+v"(A), "+v"(C));
            asm("v_permlane32_swap_b32 %0, %1" : "+v"(Bw), "+v"(D));
            u32 fr[4] = {A, Bw, C, D};
            pf[g] = *(short8*)fr;
        }

        // ---- PV swapped + l-sum via ones-A MFMA: acc col=q, row=d=crow(reg,hi)+nb*32
        __builtin_amdgcn_s_setprio(1);
#pragma unroll
        for (int g = 0; g < 4; ++g) {
            short8 vf0 = *(short8*)&Vt[lq32 * KPAD + g * 16 + hi * 8];
            short8 vf1 = *(short8*)&Vt[(32 + lq32) * KPAD + g * 16 + hi * 8];
            acc0 = __builtin_amdgcn_mfma_f32_32x32x16_bf16(vf0, pf[g], acc0, 0, 0, 0);
            acc1 = __builtin_amdgcn_mfma_f32_32x32x16_bf16(vf1, pf[g], acc1, 0, 0, 0);
            accl = __builtin_amdgcn_mfma_f32_32x32x16_bf16(ones, pf[g], accl, 0, 0, 0);
        }
        __builtin_amdgcn_s_setprio(0);
    }

    float l_run = accl[0];   // every row of accl = sum_k P[k][q]

    // ---- combine segments (seg1 -> LDS, seg0 adds), then normalize + store
    __syncthreads();
    float* cmb = (float*)KV;            // [128][65] fp32 + l[128]
    float* cl  = cmb + 128 * 65;
    const int q = qw * 32 + lq32;
    if (seg == 1) {
#pragma unroll
        for (int r = 0; r < 16; ++r) {
            const int dr = (r & 3) + 8 * (r >> 2) + 4 * hi;
            cmb[q * 65 + dr]      = acc0[r];
            cmb[q * 65 + 32 + dr] = acc1[r];
        }
        if (hi == 0) cl[q] = l_run;
    }
    __syncthreads();
    if (seg == 0) {
#pragma unroll
        for (int r = 0; r < 16; ++r) {
            const int dr = (r & 3) + 8 * (r >> 2) + 4 * hi;
            acc0[r] += cmb[q * 65 + dr];
            acc1[r] += cmb[q * 65 + 32 + dr];
        }
        l_run += cl[q];
        const float linv = 1.0f / l_run;
        ushort* T = QT;
#pragma unroll
        for (int r = 0; r < 16; ++r) {
            const int dr = (r & 3) + 8 * (r >> 2) + 4 * hi;
            T[q * KPAD + dr]      = f2b(acc0[r] * linv);
            T[q * KPAD + 32 + dr] = f2b(acc1[r] * linv);
        }
        // warp-local rows: wave-ordered LDS ops, no barrier needed
        const int r2 = qw * 32 + (lane >> 1);
        const int c0 = (lane & 1) * 32;
        const size_t g = ((size_t)(b * SS + q0 + r2)) * DD + h * DHH + c0;
#pragma unroll
        for (int j = 0; j < 4; ++j)
            *(short8*)(ctxb + g + j * 8) = *(short8*)&QT[r2 * KPAD + c0 + j * 8];
    }
}

// ---------------------------------------------------------------- launch
extern "C" void kernel_launch(void* const* d_in, const int* in_sizes, int n_in,
                              void* d_out, int out_size, void* d_ws, size_t ws_size,
                              hipStream_t stream) {
    const float* key   = (const float*)d_in[0];
    const float* value = (const float*)d_in[1];
    const float* query = (const float*)d_in[2];
    const float* Wq = (const float*)d_in[3];
    const float* bq = (const float*)d_in[4];
    const float* Wk = (const float*)d_in[5];
    const float* bk = (const float*)d_in[6];
    const float* Wv = (const float*)d_in[7];
    const float* bv = (const float*)d_in[8];
    const float* Wo = (const float*)d_in[9];
    const float* bo = (const float*)d_in[10];
    const float* rel_bias = (const float*)d_in[11];
    const void* mask = d_in[12];
    float* out = (float*)d_out;

    char* ws = (char*)d_ws;
    const size_t MB = 1024 * 1024;
    float* btbl   = (float*)(ws + 4096);                 // HH*4096 f32 = 128 KB
    u64* mwords   = (u64*)(ws + 512 * 1024);             // 2 MB
    ushort* wq_t  = (ushort*)(ws + (size_t)(3 * MB));
    ushort* wk_t  = wq_t + 512 * 512;
    ushort* wv_t  = wk_t + 512 * 512;
    ushort* wo_t  = wv_t + 512 * 512;
    ushort* q_bf  = (ushort*)(ws + (size_t)(5 * MB));
    ushort* k_bf  = q_bf + (size_t)8192 * 512;
    ushort* vT    = k_bf + (size_t)8192 * 512;
    ushort* ctx_bf = vT + (size_t)8192 * 512;

    hipLaunchKernelGGL(prep_kernel, dim3(1408), dim3(256), 0, stream,
                       mask, mwords, rel_bias, btbl,
                       Wq, Wk, Wv, Wo, wq_t, wk_t, wv_t, wo_t);

    hipLaunchKernelGGL(qkv_gemm, dim3(64, 4, 3), dim3(256), 0, stream,
                       query, key, value, wq_t, wk_t, wv_t, bq, bk, bv, q_bf, k_bf, vT);

    hipLaunchKernelGGL(attn_kernel, dim3(512), dim3(512), 0, stream,
                       q_bf, k_bf, vT, mwords, btbl, ctx_bf);

    hipLaunchKernelGGL(out_gemm, dim3(64, 4), dim3(256), 0, stream, ctx_bf, wo_t, bo, out);
}

// Round 16
// 110.258 us; speedup vs baseline: 1.1041x; 1.1041x over previous
//
#include <hip/hip_runtime.h>
#include <hip/hip_bf16.h>
#include <math.h>

#define BB 4
#define SS 2048
#define DD 512
#define HH 8
#define DHH 64
#define KPAD 72   // bf16 LDS row stride: 144B; 32-lane b128 column reads spread 8 dwords/bank = conflict-free
#define GPAD 72
#define LOG2E 1.44269504088896340736f

typedef __attribute__((ext_vector_type(8))) short short8;
typedef __attribute__((ext_vector_type(4))) float f32x4;
typedef __attribute__((ext_vector_type(16))) float f32x16;
typedef __attribute__((ext_vector_type(4))) unsigned short ushort4v;
typedef unsigned short ushort;
typedef unsigned char uchar;
typedef unsigned int u32;
typedef unsigned long long u64;

static __device__ __forceinline__ ushort f2b(float x) {
    __hip_bfloat16 h = __float2bfloat16(x);   // RNE
    return *reinterpret_cast<ushort*>(&h);
}

// ---------------------------------------------------------------- T5 bucket
__device__ __forceinline__ int t5_bucket(int rel) {
    int rb = (rel > 0) ? 16 : 0;
    int ap = rel < 0 ? -rel : rel;
    if (ap < 8) return rb + ap;
    float t = logf((float)ap * 0.125f) / 2.77258872985839844f * 8.0f;
    int large = 8 + (int)t;
    if (large > 15) large = 15;
    return rb + large;
}

// ---------------------------------------------------------------- merged prep kernel (saves 2 launches)
// bid <1024: mask->bitmask; 1024-1151: bias LUT (f32, xLOG2E); 1152-1407: weight transpose+cvt
__global__ __launch_bounds__(256) void prep_kernel(const void* __restrict__ mask, u64* __restrict__ mwords,
                                                   const float* __restrict__ rel_bias, float* __restrict__ btbl,
                                                   const float* __restrict__ W0, const float* __restrict__ W1,
                                                   const float* __restrict__ W2, const float* __restrict__ W3,
                                                   ushort* __restrict__ T0, ushort* __restrict__ T1,
                                                   ushort* __restrict__ T2, ushort* __restrict__ T3) {
    __shared__ float tile[64][65];
    __shared__ int sflag;
    const int bid = blockIdx.x;
    const int tid = threadIdx.x;

    if (bid < 1024) {
        // ---- mask -> bitmask (u64 per 64 cols), dtype detect fused
        if (tid == 0) sflag = 0;
        __syncthreads();
        u32 probe = ((const u32*)mask)[tid];      // first 1KB: bytes -> words >1 w.h.p.
        if (__any(probe > 1u) && (tid & 63) == 0) sflag = 1;
        __syncthreads();
        const bool bytemode = sflag != 0;

        int idx = bid * 256 + tid;                // (b*S + q)*32 + w
        int w = idx & 31;
        int row = idx >> 5;
        u64 bits = 0ull;
        if (bytemode) {
            const uint4* p4 = (const uint4*)((const uchar*)mask + (size_t)row * SS + w * 64);
#pragma unroll
            for (int i = 0; i < 4; ++i) {
                uint4 v = p4[i];
                unsigned int a[4] = {v.x, v.y, v.z, v.w};
#pragma unroll
                for (int j = 0; j < 4; ++j)
#pragma unroll
                    for (int byte = 0; byte < 4; ++byte)
                        if ((a[j] >> (byte * 8)) & 0xffu) bits |= 1ull << (i * 16 + j * 4 + byte);
            }
        } else {
            const int4* p4 = (const int4*)((const int*)mask + (size_t)row * SS + w * 64);
#pragma unroll
            for (int i = 0; i < 16; ++i) {
                int4 v = p4[i];
                if (v.x) bits |= 1ull << (i * 4 + 0);
                if (v.y) bits |= 1ull << (i * 4 + 1);
                if (v.z) bits |= 1ull << (i * 4 + 2);
                if (v.w) bits |= 1ull << (i * 4 + 3);
            }
        }
        mwords[idx] = bits;
    } else if (bid < 1152) {
        // ---- bias LUT: tbl[h][j], j in [0,4096): LOG2E * bias(delta = j - 2047)
        int i = (bid - 1024) * 256 + tid;
        int h = i >> 12;
        int d = (i & 4095) - 2047;
        btbl[i] = LOG2E * rel_bias[t5_bucket(d) * HH + h];
    } else {
        // ---- weight transpose + cvt: Wt[n][k] = bf16(W[k][n])
        const int b2 = bid - 1152;
        const int z = b2 >> 6;
        const float* W = z == 0 ? W0 : z == 1 ? W1 : z == 2 ? W2 : W3;
        ushort*     T = z == 0 ? T0 : z == 1 ? T1 : z == 2 ? T2 : T3;
        const int n0 = (b2 & 7) * 64, k0 = ((b2 >> 3) & 7) * 64;
        const int tr = tid >> 4, tc = tid & 15;
#pragma unroll
        for (int i = 0; i < 4; ++i) {
            int r = i * 16 + tr;
            float4 v = *(const float4*)&W[(size_t)(k0 + r) * 512 + n0 + tc * 4];
            tile[r][tc * 4 + 0] = v.x; tile[r][tc * 4 + 1] = v.y;
            tile[r][tc * 4 + 2] = v.z; tile[r][tc * 4 + 3] = v.w;
        }
        __syncthreads();
#pragma unroll
        for (int i = 0; i < 4; ++i) {
            int rn = i * 16 + tr;
            ushort4v o;
#pragma unroll
            for (int j = 0; j < 4; ++j) o[j] = f2b(tile[tc * 4 + j][rn]);
            *(ushort4v*)&T[(size_t)(n0 + rn) * 512 + k0 + tc * 4] = o;
        }
    }
}

// ---------------------------------------------------------------- merged QKV projection GEMM (bf16 MFMA), 128x128 tile
// grid (64,4,3). T14 prefetch: next K-tile loaded to regs while MFMAs run (loads no longer barrier-exposed).
__global__ __launch_bounds__(256) void qkv_gemm(const float* __restrict__ Xq, const float* __restrict__ Xk,
                                                const float* __restrict__ Xv,
                                                const ushort* __restrict__ Wqt, const ushort* __restrict__ Wkt,
                                                const ushort* __restrict__ Wvt,
                                                const float* __restrict__ bqp, const float* __restrict__ bkp,
                                                const float* __restrict__ bvp,
                                                ushort* __restrict__ Yq, ushort* __restrict__ Yk,
                                                ushort* __restrict__ Yv) {
    __shared__ ushort Als[128 * GPAD];
    __shared__ ushort Bls[128 * GPAD];
    const int z = blockIdx.z;
    const float* A    = z == 0 ? Xq : z == 1 ? Xk : Xv;
    const ushort* Bt  = z == 0 ? Wqt : z == 1 ? Wkt : Wvt;
    const float* bias = z == 0 ? bqp : z == 1 ? bkp : bvp;
    const float scale = z == 0 ? 0.125f * LOG2E : 1.0f;   // q pre-scaled into exp2 domain

    const int tid = threadIdx.x;
    const int lane = tid & 63;
    const int wid = tid >> 6;
    const int lq = lane & 15, lg = lane >> 4;
    const int wr = wid >> 1, wc = wid & 1;
    const int bm = blockIdx.x * 128;
    const int bn = blockIdx.y * 128;

    f32x4 acc[4][4];
#pragma unroll
    for (int m = 0; m < 4; ++m)
#pragma unroll
        for (int n = 0; n < 4; ++n) acc[m][n] = (f32x4){0.f, 0.f, 0.f, 0.f};

    const int sr = tid >> 3;
    const int sc = (tid & 7) * 8;

    // prologue: prefetch K-tile 0 into regs (fp32 A converted at load)
    short8 sa[4], sb[4];
#pragma unroll
    for (int i = 0; i < 4; ++i) {
        int r = sr + i * 32;
        float4 u = *(const float4*)(A + (size_t)(bm + r) * 512 + sc);
        float4 v = *(const float4*)(A + (size_t)(bm + r) * 512 + sc + 4);
        short8 av;
        av[0] = (short)f2b(u.x); av[1] = (short)f2b(u.y); av[2] = (short)f2b(u.z); av[3] = (short)f2b(u.w);
        av[4] = (short)f2b(v.x); av[5] = (short)f2b(v.y); av[6] = (short)f2b(v.z); av[7] = (short)f2b(v.w);
        sa[i] = av;
        sb[i] = *(const short8*)(Bt + (size_t)(bn + r) * 512 + sc);
    }

    for (int k0 = 0; k0 < 512; k0 += 64) {
        // commit staged tile to LDS
#pragma unroll
        for (int i = 0; i < 4; ++i) {
            int r = sr + i * 32;
            *(short8*)&Als[r * GPAD + sc] = sa[i];
            *(short8*)&Bls[r * GPAD + sc] = sb[i];
        }
        __syncthreads();
        // prefetch next K-tile (latency hides under MFMAs below)
        if (k0 < 448) {
#pragma unroll
            for (int i = 0; i < 4; ++i) {
                int r = sr + i * 32;
                float4 u = *(const float4*)(A + (size_t)(bm + r) * 512 + k0 + 64 + sc);
                float4 v = *(const float4*)(A + (size_t)(bm + r) * 512 + k0 + 64 + sc + 4);
                short8 av;
                av[0] = (short)f2b(u.x); av[1] = (short)f2b(u.y); av[2] = (short)f2b(u.z); av[3] = (short)f2b(u.w);
                av[4] = (short)f2b(v.x); av[5] = (short)f2b(v.y); av[6] = (short)f2b(v.z); av[7] = (short)f2b(v.w);
                sa[i] = av;
                sb[i] = *(const short8*)(Bt + (size_t)(bn + r) * 512 + k0 + 64 + sc);
            }
        }
#pragma unroll
        for (int kk = 0; kk < 2; ++kk) {
            short8 af[4], bf[4];
#pragma unroll
            for (int m = 0; m < 4; ++m)
                af[m] = *(short8*)&Als[(wr * 64 + m * 16 + lq) * GPAD + kk * 32 + lg * 8];
#pragma unroll
            for (int n = 0; n < 4; ++n)
                bf[n] = *(short8*)&Bls[(wc * 64 + n * 16 + lq) * GPAD + kk * 32 + lg * 8];
#pragma unroll
            for (int m = 0; m < 4; ++m)
#pragma unroll
                for (int n = 0; n < 4; ++n)
                    acc[m][n] = __builtin_amdgcn_mfma_f32_16x16x32_bf16(af[m], bf[n], acc[m][n], 0, 0, 0);
        }
        __syncthreads();   // all LDS reads done before next commit
    }

    float bv[4];
#pragma unroll
    for (int n = 0; n < 4; ++n) bv[n] = bias[bn + wc * 64 + n * 16 + lq];

    if (z == 2) {
        const int blk = bm >> 11;
        const int s0 = (bm & 2047) + wr * 64 + lg * 4;
#pragma unroll
        for (int m = 0; m < 4; ++m)
#pragma unroll
            for (int n = 0; n < 4; ++n) {
                int col = bn + wc * 64 + n * 16 + lq;
                ushort4v o;
#pragma unroll
                for (int r = 0; r < 4; ++r) o[r] = f2b(acc[m][n][r] + bv[n]);
                *(ushort4v*)&Yv[((size_t)(blk * 512 + col)) * SS + s0 + m * 16] = o;
            }
    } else {
        ushort* Y = z ? Yk : Yq;
#pragma unroll
        for (int m = 0; m < 4; ++m)
#pragma unroll
            for (int r = 0; r < 4; ++r) {
                int row = bm + wr * 64 + m * 16 + lg * 4 + r;
#pragma unroll
                for (int n = 0; n < 4; ++n) {
                    int col = bn + wc * 64 + n * 16 + lq;
                    Y[(size_t)row * 512 + col] = f2b((acc[m][n][r] + bv[n]) * scale);
                }
            }
    }
}

// ---------------------------------------------------------------- final output GEMM (bf16 A, fp32 out), 128x128, grid (64,4)
__global__ __launch_bounds__(256) void out_gemm(const ushort* __restrict__ A,
                                                const ushort* __restrict__ Bt,
                                                const float* __restrict__ bias,
                                                float* __restrict__ Y) {
    __shared__ ushort Als[128 * GPAD];
    __shared__ ushort Bls[128 * GPAD];
    const int tid = threadIdx.x;
    const int lane = tid & 63;
    const int wid = tid >> 6;
    const int lq = lane & 15, lg = lane >> 4;
    const int wr = wid >> 1, wc = wid & 1;
    const int bm = blockIdx.x * 128;
    const int bn = blockIdx.y * 128;

    f32x4 acc[4][4];
#pragma unroll
    for (int m = 0; m < 4; ++m)
#pragma unroll
        for (int n = 0; n < 4; ++n) acc[m][n] = (f32x4){0.f, 0.f, 0.f, 0.f};

    const int sr = tid >> 3;
    const int sc = (tid & 7) * 8;

    // prologue: prefetch K-tile 0
    short8 sa[4], sb[4];
#pragma unroll
    for (int i = 0; i < 4; ++i) {
        int r = sr + i * 32;
        sa[i] = *(const short8*)(A + (size_t)(bm + r) * 512 + sc);
        sb[i] = *(const short8*)(Bt + (size_t)(bn + r) * 512 + sc);
    }

    for (int k0 = 0; k0 < 512; k0 += 64) {
#pragma unroll
        for (int i = 0; i < 4; ++i) {
            int r = sr + i * 32;
            *(short8*)&Als[r * GPAD + sc] = sa[i];
            *(short8*)&Bls[r * GPAD + sc] = sb[i];
        }
        __syncthreads();
        if (k0 < 448) {
#pragma unroll
            for (int i = 0; i < 4; ++i) {
                int r = sr + i * 32;
                sa[i] = *(const short8*)(A + (size_t)(bm + r) * 512 + k0 + 64 + sc);
                sb[i] = *(const short8*)(Bt + (size_t)(bn + r) * 512 + k0 + 64 + sc);
            }
        }
#pragma unroll
        for (int kk = 0; kk < 2; ++kk) {
            short8 af[4], bf[4];
#pragma unroll
            for (int m = 0; m < 4; ++m)
                af[m] = *(short8*)&Als[(wr * 64 + m * 16 + lq) * GPAD + kk * 32 + lg * 8];
#pragma unroll
            for (int n = 0; n < 4; ++n)
                bf[n] = *(short8*)&Bls[(wc * 64 + n * 16 + lq) * GPAD + kk * 32 + lg * 8];
#pragma unroll
            for (int m = 0; m < 4; ++m)
#pragma unroll
                for (int n = 0; n < 4; ++n)
                    acc[m][n] = __builtin_amdgcn_mfma_f32_16x16x32_bf16(af[m], bf[n], acc[m][n], 0, 0, 0);
        }
        __syncthreads();
    }

    float bv[4];
#pragma unroll
    for (int n = 0; n < 4; ++n) bv[n] = bias[bn + wc * 64 + n * 16 + lq];
#pragma unroll
    for (int m = 0; m < 4; ++m)
#pragma unroll
        for (int r = 0; r < 4; ++r) {
            int row = bm + wr * 64 + m * 16 + lg * 4 + r;
#pragma unroll
            for (int n = 0; n < 4; ++n) {
                int col = bn + wc * 64 + n * 16 + lq;
                Y[(size_t)row * 512 + col] = acc[m][n][r] + bv[n];
            }
        }
}

// ---------------------------------------------------------------- MFMA flash attention (byte-exact r13/r14 structure, 62.1us proven; NO setprio — r15 lesson)
// 512 thr (8 warps), split-KV, 128 q-rows/block, swapped QK^T/PV (lane = q), fixed-max exp2 softmax.
// Bias folded into QK MFMA C-input (f32 LDS reads). Mask = branchless sign-extend AND.
// l = sum_k p via all-ones-A MFMA. Pack via v_cvt_pk_bf16_f32; half-exchange via permlane32_swap.
// LESSONS: launch_bounds (512,4) only (r10 spill); no const-bias branch (r11 spill); KPAD=72 everywhere (r12);
// NO setprio — this kernel is barrier-lockstep per block, the m190 null/negative regime (r15: −16us, FETCH +8MB).
__global__ __launch_bounds__(512, 4) void attn_kernel(const ushort* __restrict__ Qg, const ushort* __restrict__ Kg,
                                                      const ushort* __restrict__ vT, const u64* __restrict__ mwords,
                                                      const float* __restrict__ btbl, ushort* __restrict__ ctxb) {
    __shared__ ushort KV[4][64 * KPAD];   // K0,K1,V0,V1; reused as fp32 combine buffer
    __shared__ ushort QT[128 * KPAD];     // Q staging -> f32 bias table (16KB) -> epilogue transpose
    float* tbl = (float*)QT;

    const int bid = blockIdx.x;                       // grid = 512
    const int wk = ((bid & 7) << 6) | (bid >> 3);     // XCD-chunked remap (512 % 8 == 0: bijective)
    const int qb = wk & 15;
    const int h  = (wk >> 4) & 7;
    const int b  = wk >> 7;
    const int q0 = qb * 128;

    const int tid  = threadIdx.x;
    const int wid  = tid >> 6;
    const int lane = tid & 63;
    const int lq32 = lane & 31;
    const int hi   = lane >> 5;
    const int seg  = wid >> 2;
    const int qw   = wid & 3;

    const u64* mrow = mwords + (size_t)b * SS * 32;
    const int qg = q0 + qw * 32 + lq32;

    // ---- stage Q tile (128 x 64)
    {
        const int r = tid >> 2;
        const int c = (tid & 3) * 16;
        const size_t g = ((size_t)(b * SS + q0 + r)) * DD + h * DHH + c;
        *(short8*)&QT[r * KPAD + c]     = *(const short8*)(Qg + g);
        *(short8*)&QT[r * KPAD + c + 8] = *(const short8*)(Qg + g + 8);
    }
    __syncthreads();

    short8 qf[4];
#pragma unroll
    for (int dch = 0; dch < 4; ++dch)
        qf[dch] = *(short8*)&QT[(qw * 32 + lq32) * KPAD + dch * 16 + hi * 8];
    __syncthreads();   // all Q reads done before bias table overwrites QT

    // ---- f32 bias table for this head -> LDS (16 KB)
    {
        const float4* src = (const float4*)(btbl + (size_t)h * 4096);
        float4* dst = (float4*)tbl;
        dst[tid]       = src[tid];
        dst[tid + 512] = src[tid + 512];
    }

    f32x16 acc0, acc1, accl;
#pragma unroll
    for (int i = 0; i < 16; ++i) { acc0[i] = 0.f; acc1[i] = 0.f; accl[i] = 0.f; }

    short8 ones;
#pragma unroll
    for (int i = 0; i < 8; ++i) ones[i] = (short)0x3F80;   // bf16 1.0

    // staging role: tile = tid>>7 (0:K0 1:K1 2:V0 3:V1), wave-uniform
    const int stile = tid >> 7;
    const int sidx = tid & 127;
    const int srow = sidx >> 1;
    const int scol = (sidx & 1) * 32;
    const size_t kbaseK = ((size_t)(b * SS + (stile & 1) * 1024 + srow)) * DD + h * DHH + scol;
    const size_t kbaseV = ((size_t)(b * DD + h * DHH + srow)) * SS + (stile & 1) * 1024 + scol;

    // prologue: prefetch tile 0 into regs
    short8 stg[4];
    {
        const ushort* sp = (stile < 2) ? (Kg + kbaseK) : (vT + kbaseV);
#pragma unroll
        for (int j = 0; j < 4; ++j) stg[j] = *(const short8*)(sp + j * 8);
    }

    const float* tbp_base = tbl + (2047 + hi * 4 - qg);

    for (int t = 0; t < 16; ++t) {
        __syncthreads();   // prev tiles consumed (t=0: bias table stores complete)
        {
            ushort* dst = &KV[stile][srow * KPAD + scol];
#pragma unroll
            for (int j = 0; j < 4; ++j) *(short8*)(dst + j * 8) = stg[j];
        }
        __syncthreads();
        if (t < 15) {   // prefetch t+1 (latency hides under compute below)
            const ushort* sp = (stile < 2) ? (Kg + kbaseK + (size_t)(t + 1) * 64 * DD)
                                           : (vT + kbaseV + (t + 1) * 64);
#pragma unroll
            for (int j = 0; j < 4; ++j) stg[j] = *(const short8*)(sp + j * 8);
        }

        const ushort* Ks = KV[seg];
        const ushort* Vt = KV[2 + seg];
        const int ktw = seg * 16 + t;
        const u64 wv = mrow[(size_t)qg * 32 + ktw];

        // ---- QK^T swapped, C initialized with bias (exp2 domain): col=q, row=k=crow(reg,hi)+sub*32
        const float* tbp = tbp_base + ktw * 64;
        f32x16 st0, st1;
#pragma unroll
        for (int r = 0; r < 16; ++r) {
            const int br = (r & 3) + 8 * (r >> 2);
            st0[r] = tbp[br];
            st1[r] = tbp[32 + br];
        }
#pragma unroll
        for (int dch = 0; dch < 4; ++dch) {
            short8 kf0 = *(short8*)&Ks[lq32 * KPAD + dch * 16 + hi * 8];
            short8 kf1 = *(short8*)&Ks[(32 + lq32) * KPAD + dch * 16 + hi * 8];
            st0 = __builtin_amdgcn_mfma_f32_32x32x16_bf16(kf0, qf[dch], st0, 0, 0, 0);
            st1 = __builtin_amdgcn_mfma_f32_32x32x16_bf16(kf1, qf[dch], st1, 0, 0, 0);
        }

        // ---- exp2 + branchless mask-zero (keep = sext of inverted mask bit)
        const u32 mi0 = ~(((u32)wv) >> (hi * 4));
        const u32 mi1 = ~(((u32)(wv >> 32)) >> (hi * 4));
        float p0[16], p1[16];
#pragma unroll
        for (int r = 0; r < 16; ++r) {
            const int br = (r & 3) + 8 * (r >> 2);
            float e0 = __builtin_amdgcn_exp2f(st0[r]);
            float e1 = __builtin_amdgcn_exp2f(st1[r]);
            u32 k0 = (u32)(((int)(mi0 << (31 - br))) >> 31);
            u32 k1 = (u32)(((int)(mi1 << (31 - br))) >> 31);
            p0[r] = __uint_as_float(__float_as_uint(e0) & k0);
            p1[r] = __uint_as_float(__float_as_uint(e1) & k1);
        }

        // ---- pack P pairs via v_cvt_pk_bf16_f32; half-exchange via permlane32_swap
        u32 W[16];
#pragma unroll
        for (int w = 0; w < 8; ++w) {
            asm("v_cvt_pk_bf16_f32 %0, %1, %2" : "=v"(W[w])     : "v"(p0[2 * w]), "v"(p0[2 * w + 1]));
            asm("v_cvt_pk_bf16_f32 %0, %1, %2" : "=v"(W[8 + w]) : "v"(p1[2 * w]), "v"(p1[2 * w + 1]));
        }
        short8 pf[4];
#pragma unroll
        for (int g = 0; g < 4; ++g) {
            u32 A = W[g * 4 + 0], Bw = W[g * 4 + 1], C = W[g * 4 + 2], D = W[g * 4 + 3];
            asm("v_permlane32_swap_b32 %0, %1" : "+v"(A), "+v"(C));
            asm("v_permlane32_swap_b32 %0, %1" : "+v"(Bw), "+v"(D));
            u32 fr[4] = {A, Bw, C, D};
            pf[g] = *(short8*)fr;
        }

        // ---- PV swapped + l-sum via ones-A MFMA: acc col=q, row=d=crow(reg,hi)+nb*32
#pragma unroll
        for (int g = 0; g < 4; ++g) {
            short8 vf0 = *(short8*)&Vt[lq32 * KPAD + g * 16 + hi * 8];
            short8 vf1 = *(short8*)&Vt[(32 + lq32) * KPAD + g * 16 + hi * 8];
            acc0 = __builtin_amdgcn_mfma_f32_32x32x16_bf16(vf0, pf[g], acc0, 0, 0, 0);
            acc1 = __builtin_amdgcn_mfma_f32_32x32x16_bf16(vf1, pf[g], acc1, 0, 0, 0);
            accl = __builtin_amdgcn_mfma_f32_32x32x16_bf16(ones, pf[g], accl, 0, 0, 0);
        }
    }

    float l_run = accl[0];   // every row of accl = sum_k P[k][q]

    // ---- combine segments (seg1 -> LDS, seg0 adds), then normalize + store
    __syncthreads();
    float* cmb = (float*)KV;            // [128][65] fp32 + l[128]
    float* cl  = cmb + 128 * 65;
    const int q = qw * 32 + lq32;
    if (seg == 1) {
#pragma unroll
        for (int r = 0; r < 16; ++r) {
            const int dr = (r & 3) + 8 * (r >> 2) + 4 * hi;
            cmb[q * 65 + dr]      = acc0[r];
            cmb[q * 65 + 32 + dr] = acc1[r];
        }
        if (hi == 0) cl[q] = l_run;
    }
    __syncthreads();
    if (seg == 0) {
#pragma unroll
        for (int r = 0; r < 16; ++r) {
            const int dr = (r & 3) + 8 * (r >> 2) + 4 * hi;
            acc0[r] += cmb[q * 65 + dr];
            acc1[r] += cmb[q * 65 + 32 + dr];
        }
        l_run += cl[q];
        const float linv = 1.0f / l_run;
        ushort* T = QT;
#pragma unroll
        for (int r = 0; r < 16; ++r) {
            const int dr = (r & 3) + 8 * (r >> 2) + 4 * hi;
            T[q * KPAD + dr]      = f2b(acc0[r] * linv);
            T[q * KPAD + 32 + dr] = f2b(acc1[r] * linv);
        }
        // warp-local rows: wave-ordered LDS ops, no barrier needed
        const int r2 = qw * 32 + (lane >> 1);
        const int c0 = (lane & 1) * 32;
        const size_t g = ((size_t)(b * SS + q0 + r2)) * DD + h * DHH + c0;
#pragma unroll
        for (int j = 0; j < 4; ++j)
            *(short8*)(ctxb + g + j * 8) = *(short8*)&QT[r2 * KPAD + c0 + j * 8];
    }
}

// ---------------------------------------------------------------- launch
extern "C" void kernel_launch(void* const* d_in, const int* in_sizes, int n_in,
                              void* d_out, int out_size, void* d_ws, size_t ws_size,
                              hipStream_t stream) {
    const float* key   = (const float*)d_in[0];
    const float* value = (const float*)d_in[1];
    const float* query = (const float*)d_in[2];
    const float* Wq = (const float*)d_in[3];
    const float* bq = (const float*)d_in[4];
    const float* Wk = (const float*)d_in[5];
    const float* bk = (const float*)d_in[6];
    const float* Wv = (const float*)d_in[7];
    const float* bv = (const float*)d_in[8];
    const float* Wo = (const float*)d_in[9];
    const float* bo = (const float*)d_in[10];
    const float* rel_bias = (const float*)d_in[11];
    const void* mask = d_in[12];
    float* out = (float*)d_out;

    char* ws = (char*)d_ws;
    const size_t MB = 1024 * 1024;
    float* btbl   = (float*)(ws + 4096);                 // HH*4096 f32 = 128 KB
    u64* mwords   = (u64*)(ws + 512 * 1024);             // 2 MB
    ushort* wq_t  = (ushort*)(ws + (size_t)(3 * MB));
    ushort* wk_t  = wq_t + 512 * 512;
    ushort* wv_t  = wk_t + 512 * 512;
    ushort* wo_t  = wv_t + 512 * 512;
    ushort* q_bf  = (ushort*)(ws + (size_t)(5 * MB));
    ushort* k_bf  = q_bf + (size_t)8192 * 512;
    ushort* vT    = k_bf + (size_t)8192 * 512;
    ushort* ctx_bf = vT + (size_t)8192 * 512;

    hipLaunchKernelGGL(prep_kernel, dim3(1408), dim3(256), 0, stream,
                       mask, mwords, rel_bias, btbl,
                       Wq, Wk, Wv, Wo, wq_t, wk_t, wv_t, wo_t);

    hipLaunchKernelGGL(qkv_gemm, dim3(64, 4, 3), dim3(256), 0, stream,
                       query, key, value, wq_t, wk_t, wv_t, bq, bk, bv, q_bf, k_bf, vT);

    hipLaunchKernelGGL(attn_kernel, dim3(512), dim3(512), 0, stream,
                       q_bf, k_bf, vT, mwords, btbl, ctx_bf);

    hipLaunchKernelGGL(out_gemm, dim3(64, 4), dim3(256), 0, stream, ctx_bf, wo_t, bo, out);
}